// Round 17
// baseline (154.523 us; speedup 1.0000x reference)
//
#include <hip/hip_runtime.h>

#define IMG_W 1024
#define IMG_H 1024
#define NFRAMES 32
#define CROP 4
#define RPB 32
#define RING 8               // per-wave ring slots (power of 2)
#define CHUNK 848            // 53 lanes x 16B per row per tensor
#define SLOTB (2*CHUNK)      // A chunk then B chunk = 1696 B
#define WRING (RING*SLOTB)   // 13568 B per wave
#define WAVES 5              // 5*13568 = 67840 B -> 2 blocks/CU

__device__ __forceinline__ void gl_lds16(const float* g, void* l) {
    __builtin_amdgcn_global_load_lds(
        (const __attribute__((address_space(1))) void*)g,
        (__attribute__((address_space(3))) void*)l,
        16, 0, 0);
}

__global__ __launch_bounds__(64 * WAVES) void gimbaless_sums(
    const float* __restrict__ A, const float* __restrict__ B,
    const float* __restrict__ lp9, double* __restrict__ sums)
{
    __shared__ __align__(16) unsigned char smem[WAVES * WRING];

    const int tid  = threadIdx.x;
    const int w    = tid >> 6;
    const int lane = tid & 63;
    const int band = blockIdx.x;
    const int t    = blockIdx.y;
    const float* a = A + (size_t)t * (IMG_W * IMG_H);
    const float* b = B + (size_t)t * (IMG_W * IMG_H);

    const float lp0 = lp9[0], lp1 = lp9[1], lp2 = lp9[2], lp3 = lp9[3], lp4 = lp9[4];

    const int r0   = CROP + band * RPB;
    const int rend = min(r0 + RPB, IMG_H - CROP);

    // column mapping (verified in R12): wave w stages cols [sbase, +211]
    const int sbase = (w < 4) ? 204 * w : 816;
    const int nst   = (w < 4) ? 53 : 52;           // staging lanes
    const int nact  = (w < 4) ? 51 : 50;           // compute lanes
    const int col0  = 4 + 204 * w + 4 * lane;
    const bool active = (lane < nact);
    const int co = 16 + (lane << 4);
    const float x0 = (float)col0 - 511.5f;

    unsigned char* wbase = smem + w * WRING;

    auto stage = [&](int r) {
        const int slot = r & (RING - 1);
        if (lane < nst) {
            gl_lds16(a + (size_t)r * IMG_W + sbase + (lane << 2), wbase + slot * SLOTB);
            gl_lds16(b + (size_t)r * IMG_W + sbase + (lane << 2), wbase + slot * SLOTB + CHUNK);
        }
    };
    auto rdA = [&](int slot, int off) -> float4 {
        return *(const float4*)(wbase + slot * SLOTB + off);
    };
    auto rdB = [&](int slot, int off) -> float4 {
        return *(const float4*)(wbase + slot * SLOTB + CHUNK + off);
    };

    float s0=0.f,s1=0.f,s2=0.f,s3=0.f,s4=0.f,s5=0.f,s6=0.f,s7=0.f,s8=0.f;
    float d[9][4];    // dif rows h-4..h+4
    float av[6][4];   // avg rows h-1..h+4

    // ---- prologue: fill 8-slot ring with rows r0-4 .. r0+3 ----
    for (int r = r0 - 4; r <= r0 + 3; ++r) stage(r);
    asm volatile("s_waitcnt vmcnt(0)" ::: "memory");
    if (active) {
#pragma unroll
        for (int k = 0; k < 8; ++k) {
            const int slot = (r0 - 4 + k) & (RING - 1);
            float4 va = rdA(slot, co);
            float4 vb = rdB(slot, co);
            d[k][0]=va.x-vb.x; d[k][1]=va.y-vb.y; d[k][2]=va.z-vb.z; d[k][3]=va.w-vb.w;
            if (k >= 3) {
                av[k-3][0]=(va.x+vb.x)*0.5f; av[k-3][1]=(va.y+vb.y)*0.5f;
                av[k-3][2]=(va.z+vb.z)*0.5f; av[k-3][3]=(va.w+vb.w)*0.5f;
            }
        }
    }
    asm volatile("s_waitcnt lgkmcnt(0)" ::: "memory");   // window reads landed
    // lead-3: stage rows r0+4..r0+6 into slots of r0-4..r0-2 (reads done)
    stage(r0 + 4); stage(r0 + 5); stage(r0 + 6);         // 6 gl_lds outstanding

    // ---- main loop: per-wave self-paced, counted vmcnt, NO barriers ----
#pragma unroll 1
    for (int h = r0; h < rend; ++h) {
        // FIFO vmcnt: complete stage(h+4) (oldest), keep h+5,h+6 in flight
        if (h < rend - 2)       asm volatile("s_waitcnt vmcnt(4)" ::: "memory");
        else if (h == rend - 2) asm volatile("s_waitcnt vmcnt(2)" ::: "memory");
        else                    asm volatile("s_waitcnt vmcnt(0)" ::: "memory");

        const int sl  = h & (RING - 1);
        const int sl4 = (h + 4) & (RING - 1);

        float4 na, nb, la, lb, ra, rb;
        if (active) {
            na = rdA(sl4, co);      nb = rdB(sl4, co);      // narrow h+4
            la = rdA(sl, co - 16);  lb = rdB(sl, co - 16);  // halos row h
            ra = rdA(sl, co + 16);  rb = rdB(sl, co + 16);
        }
        asm volatile("s_waitcnt lgkmcnt(0)" ::: "memory");  // reads in registers
        if (h <= rend - 4) stage(h + 7);   // slot of row h-1 (reads drained)

        if (active) {
            d[8][0]=na.x-nb.x; d[8][1]=na.y-nb.y; d[8][2]=na.z-nb.z; d[8][3]=na.w-nb.w;
            av[5][0]=(na.x+nb.x)*0.5f; av[5][1]=(na.y+nb.y)*0.5f;
            av[5][2]=(na.z+nb.z)*0.5f; av[5][3]=(na.w+nb.w)*0.5f;

            float dc[12], avc[6];
            dc[0]=la.x-lb.x; dc[1]=la.y-lb.y; dc[2]=la.z-lb.z; dc[3]=la.w-lb.w;
            dc[4]=d[4][0]; dc[5]=d[4][1]; dc[6]=d[4][2]; dc[7]=d[4][3];
            dc[8]=ra.x-rb.x; dc[9]=ra.y-rb.y; dc[10]=ra.z-rb.z; dc[11]=ra.w-rb.w;
            avc[0]=(la.w+lb.w)*0.5f;
            avc[1]=av[1][0]; avc[2]=av[1][1]; avc[3]=av[1][2]; avc[4]=av[1][3];
            avc[5]=(ra.x+rb.x)*0.5f;

            const float y = (float)h - 511.5f;
#pragma unroll
            for (int j = 0; j < 4; ++j) {
                const float px = (avc[j] - avc[j + 2]) * 0.5f;
                const float py = (av[0][j] - av[2][j]) * 0.5f;
                float ax = lp4 * dc[j + 4];
                ax = fmaf(lp0, dc[j] + dc[j + 8], ax);
                ax = fmaf(lp1, dc[j + 1] + dc[j + 7], ax);
                ax = fmaf(lp2, dc[j + 2] + dc[j + 6], ax);
                ax = fmaf(lp3, dc[j + 3] + dc[j + 5], ax);
                float ay = lp4 * d[4][j];
                ay = fmaf(lp0, d[0][j] + d[8][j], ay);
                ay = fmaf(lp1, d[1][j] + d[7][j], ay);
                ay = fmaf(lp2, d[2][j] + d[6][j], ay);
                ay = fmaf(lp3, d[3][j] + d[5][j], ay);

                const float x = x0 + (float)j;
                const float mom = px * y - py * x;
                s0 = fmaf(px, px, s0);
                s1 = fmaf(px, py, s1);
                s2 = fmaf(px, mom, s2);
                s3 = fmaf(py, py, s3);
                s4 = fmaf(py, mom, s4);
                s5 = fmaf(mom, mom, s5);
                const float tx = ax * px;
                const float ty = ay * py;
                s6 += tx;
                s7 += ty;
                s8 += tx * y - ty * x;
            }

#pragma unroll
            for (int k = 0; k < 8; ++k) {
                d[k][0]=d[k+1][0]; d[k][1]=d[k+1][1]; d[k][2]=d[k+1][2]; d[k][3]=d[k+1][3];
            }
#pragma unroll
            for (int k = 0; k < 5; ++k) {
                av[k][0]=av[k+1][0]; av[k][1]=av[k+1][1]; av[k][2]=av[k+1][2]; av[k][3]=av[k+1][3];
            }
        }
    }

    // ---- reduction: f64 wave shuffle -> LDS (aliased) -> global atomic ----
    double ds[9];
    ds[0]=s0; ds[1]=s1; ds[2]=s2; ds[3]=s3; ds[4]=s4;
    ds[5]=s5; ds[6]=s6; ds[7]=s7; ds[8]=s8;
#pragma unroll
    for (int k = 0; k < 9; ++k) {
        double x = ds[k];
        for (int off = 32; off > 0; off >>= 1)
            x += __shfl_down(x, off);
        ds[k] = x;
    }
    __syncthreads();                          // all waves done (full vm+lgkm drain)
    double (*red)[9] = (double(*)[9])smem;    // alias ring buffer
    if (lane == 0) {
#pragma unroll
        for (int k = 0; k < 9; ++k) red[w][k] = ds[k];
    }
    __syncthreads();
    if (tid < 9) {
        double tot = 0.0;
#pragma unroll
        for (int q = 0; q < WAVES; ++q) tot += red[q][tid];
        atomicAdd(&sums[(size_t)t * 9 + tid], tot);
    }
}

__global__ void gimbaless_solve(const double* __restrict__ sums, float* __restrict__ out)
{
    const int t = threadIdx.x;
    if (t < NFRAMES) {
        const double* s = sums + (size_t)t * 9;
        const double m00=s[0], m01=s[1], m02=s[2], m11=s[3], m12=s[4], m22=s[5];
        const double b0=s[6], b1=s[7], b2=s[8];
        const double c00 = m11*m22 - m12*m12;
        const double c01 = m02*m12 - m01*m22;
        const double c02 = m01*m12 - m02*m11;
        const double c11 = m00*m22 - m02*m02;
        const double c12 = m01*m02 - m00*m12;
        const double c22 = m00*m11 - m01*m01;
        const double det = m00*c00 + m01*c01 + m02*c02;
        const double inv = 1.0 / det;
        out[t]             = (float)((c00*b0 + c01*b1 + c02*b2) * inv);
        out[NFRAMES + t]   = (float)((c01*b0 + c11*b1 + c12*b2) * inv);
        out[2*NFRAMES + t] = (float)((c02*b0 + c12*b1 + c22*b2) * inv);
    }
}

extern "C" void kernel_launch(void* const* d_in, const int* in_sizes, int n_in,
                              void* d_out, int out_size, void* d_ws, size_t ws_size,
                              hipStream_t stream) {
    const float* A  = (const float*)d_in[0];
    const float* B  = (const float*)d_in[1];
    const float* lp = (const float*)d_in[2];
    double* sums = (double*)d_ws;

    (void)hipMemsetAsync(d_ws, 0, NFRAMES * 9 * sizeof(double), stream);

    dim3 grid((IMG_H - 2*CROP + RPB - 1) / RPB, NFRAMES);  // (32, 32)
    gimbaless_sums<<<grid, 64 * WAVES, 0, stream>>>(A, B, lp, sums);
    gimbaless_solve<<<1, 64, 0, stream>>>(sums, (float*)d_out);
}

// Round 18
// 106.675 us; speedup vs baseline: 1.4485x; 1.4485x over previous
//
#include <hip/hip_runtime.h>

#define IMG_W 1024
#define IMG_H 1024
#define NFRAMES 32
#define CROP 4
#define RPB 32          // rows per band; 32 bands x 2 halves x 32 frames = 2048 blocks
#define RING 6
#define CHUNKB 2048     // 512 cols x 4B staged per row per tensor
#define SLOTB 4096      // A chunk + B chunk
#define ABYTES (RING*SLOTB)   // 24576 B -> 6 blocks/CU

typedef __attribute__((ext_vector_type(4))) float f32x4;

__device__ __forceinline__ f32x4 ldg4(const float* p) {
    return *reinterpret_cast<const f32x4*>(p);
}

__device__ __forceinline__ void gl_lds16(const float* g, void* l) {
    __builtin_amdgcn_global_load_lds(
        (const __attribute__((address_space(1))) void*)g,
        (__attribute__((address_space(3))) void*)l,
        16, 0, 0);
}

__global__ __launch_bounds__(128) void gimbaless_sums(
    const float* __restrict__ A, const float* __restrict__ B,
    const float* __restrict__ lp9, double* __restrict__ sums)
{
    __shared__ __align__(16) unsigned char smem[ABYTES];

    const int tid  = threadIdx.x;              // 0..127
    const int band = blockIdx.x >> 1;
    const int BASE = (blockIdx.x & 1) << 9;    // 0 or 512
    const int t    = blockIdx.y;
    const float* a = A + (size_t)t * (IMG_W * IMG_H);
    const float* b = B + (size_t)t * (IMG_W * IMG_H);

    const float lp0 = lp9[0], lp1 = lp9[1], lp2 = lp9[2], lp3 = lp9[3], lp4 = lp9[4];

    const int r0   = CROP + band * RPB;
    const int rend = min(r0 + RPB, IMG_H - CROP);   // 32 or 24 rows, even

    const int co  = tid * 16;                  // own quad byte offset in chunk
    const int coL = max(co - 16, 0);           // clamped (edge value overridden)
    const int coR = min(co + 16, CHUNKB - 16);
    const int wb  = (tid >> 6) * 1024;         // wave-uniform LDS sub-base

    const int col0 = BASE + 4 * tid;           // lane's first col
    const bool active = (col0 >= 4) && (col0 <= 1016);
    const bool isL = (tid == 0);               // needs global left halo (if BASE>0)
    const bool isR = (tid == 127);             // needs global right halo (if BASE==0)
    const int hcol = isL ? max(BASE - 4, 0) : (BASE + 512);  // halo col base
    const float x0 = (float)col0 - 511.5f;

    auto stage = [&](int r) {                  // DMA 512-col chunk of A and B
        const int slot = r % RING;
        gl_lds16(a + (size_t)r * IMG_W + BASE + tid * 4, smem + slot * SLOTB + wb);
        gl_lds16(b + (size_t)r * IMG_W + BASE + tid * 4, smem + slot * SLOTB + CHUNKB + wb);
    };
    auto rdA = [&](int slot, int off) -> f32x4 {
        return *(const f32x4*)(smem + slot * SLOTB + off);
    };
    auto rdB = [&](int slot, int off) -> f32x4 {
        return *(const f32x4*)(smem + slot * SLOTB + CHUNKB + off);
    };

    float s0=0.f,s1=0.f,s2=0.f,s3=0.f,s4=0.f,s5=0.f,s6=0.f,s7=0.f,s8=0.f;
    float d[10][4];   // dif rows h-4 .. h+5
    float av[7][4];   // avg rows h-1 .. h+5

    // ---- prologue: fill window rows r0-4..r0+3 ----
    for (int r = r0 - 4; r <= r0 + 1; ++r) stage(r);          // 6 rows fill ring
    asm volatile("s_waitcnt vmcnt(0)" ::: "memory");
#pragma unroll
    for (int k = 0; k < 6; ++k) {
        const int slot = (r0 - 4 + k) % RING;
        f32x4 va = rdA(slot, co);
        f32x4 vb = rdB(slot, co);
        d[k][0]=va.x-vb.x; d[k][1]=va.y-vb.y; d[k][2]=va.z-vb.z; d[k][3]=va.w-vb.w;
        if (k >= 3) {
            av[k-3][0]=(va.x+vb.x)*0.5f; av[k-3][1]=(va.y+vb.y)*0.5f;
            av[k-3][2]=(va.z+vb.z)*0.5f; av[k-3][3]=(va.w+vb.w)*0.5f;
        }
    }
    asm volatile("s_waitcnt lgkmcnt(0)" ::: "memory");
    stage(r0 + 2); stage(r0 + 3); stage(r0 + 4); stage(r0 + 5);
    asm volatile("s_waitcnt vmcnt(4)" ::: "memory");          // r0+2,r0+3 arrived
#pragma unroll
    for (int k = 6; k < 8; ++k) {
        const int slot = (r0 - 4 + k) % RING;
        f32x4 va = rdA(slot, co);
        f32x4 vb = rdB(slot, co);
        d[k][0]=va.x-vb.x; d[k][1]=va.y-vb.y; d[k][2]=va.z-vb.z; d[k][3]=va.w-vb.w;
        av[k-3][0]=(va.x+vb.x)*0.5f; av[k-3][1]=(va.y+vb.y)*0.5f;
        av[k-3][2]=(va.z+vb.z)*0.5f; av[k-3][3]=(va.w+vb.w)*0.5f;
    }
    // in flight entering loop: stage(r0+4), stage(r0+5)

    // ---- main loop: 2 rows per epoch ----
#pragma unroll 1
    for (int h = r0; h < rend; h += 2) {
        // edge lanes: global halo quads for rows h, h+1 (L2-hot neighbor data)
        f32x4 ghA0, ghB0, ghA1, ghB1;
        if (isL | isR) {
            ghA0 = ldg4(a + (size_t)h * IMG_W + hcol);
            ghB0 = ldg4(b + (size_t)h * IMG_W + hcol);
            ghA1 = ldg4(a + (size_t)(h + 1) * IMG_W + hcol);
            ghB1 = ldg4(b + (size_t)(h + 1) * IMG_W + hcol);
        }

        asm volatile("s_waitcnt vmcnt(0)" ::: "memory");  // rows h+4,h+5 (+halos) done
        __builtin_amdgcn_s_barrier();                     // chunks visible to both waves

        const int m0 = h % RING;
        const int m1 = (h + 1) % RING;
        const int m4 = (h + 4) % RING;
        const int m5 = (h + 5) % RING;

        f32x4 na0 = rdA(m4, co),  nb0 = rdB(m4, co);      // narrow h+4
        f32x4 na1 = rdA(m5, co),  nb1 = rdB(m5, co);      // narrow h+5
        f32x4 la0 = rdA(m0, coL), lb0 = rdB(m0, coL);     // halos row h
        f32x4 ra0 = rdA(m0, coR), rb0 = rdB(m0, coR);
        f32x4 la1 = rdA(m1, coL), lb1 = rdB(m1, coL);     // halos row h+1
        f32x4 ra1 = rdA(m1, coR), rb1 = rdB(m1, coR);
        asm volatile("s_waitcnt lgkmcnt(0)" ::: "memory");
        __builtin_amdgcn_s_barrier();                     // safe to overwrite m0,m1

        if (h + 2 < rend) { stage(h + 6); stage(h + 7); } // DMA under compute

        // edge overrides (selected values; inactive lanes don't matter)
        if (isL) { la0 = ghA0; lb0 = ghB0; la1 = ghA1; lb1 = ghB1; }
        if (isR) { ra0 = ghA0; rb0 = ghB0; ra1 = ghA1; rb1 = ghB1; }

        if (active) {
            d[8][0]=na0.x-nb0.x; d[8][1]=na0.y-nb0.y; d[8][2]=na0.z-nb0.z; d[8][3]=na0.w-nb0.w;
            av[5][0]=(na0.x+nb0.x)*0.5f; av[5][1]=(na0.y+nb0.y)*0.5f;
            av[5][2]=(na0.z+nb0.z)*0.5f; av[5][3]=(na0.w+nb0.w)*0.5f;
            d[9][0]=na1.x-nb1.x; d[9][1]=na1.y-nb1.y; d[9][2]=na1.z-nb1.z; d[9][3]=na1.w-nb1.w;
            av[6][0]=(na1.x+nb1.x)*0.5f; av[6][1]=(na1.y+nb1.y)*0.5f;
            av[6][2]=(na1.z+nb1.z)*0.5f; av[6][3]=(na1.w+nb1.w)*0.5f;

#pragma unroll
            for (int rr = 0; rr < 2; ++rr) {
                float dc[12], avc[6];
                if (rr == 0) {
                    dc[0]=la0.x-lb0.x; dc[1]=la0.y-lb0.y; dc[2]=la0.z-lb0.z; dc[3]=la0.w-lb0.w;
                    dc[4]=d[4][0]; dc[5]=d[4][1]; dc[6]=d[4][2]; dc[7]=d[4][3];
                    dc[8]=ra0.x-rb0.x; dc[9]=ra0.y-rb0.y; dc[10]=ra0.z-rb0.z; dc[11]=ra0.w-rb0.w;
                    avc[0]=(la0.w+lb0.w)*0.5f;
                    avc[1]=av[1][0]; avc[2]=av[1][1]; avc[3]=av[1][2]; avc[4]=av[1][3];
                    avc[5]=(ra0.x+rb0.x)*0.5f;
                } else {
                    dc[0]=la1.x-lb1.x; dc[1]=la1.y-lb1.y; dc[2]=la1.z-lb1.z; dc[3]=la1.w-lb1.w;
                    dc[4]=d[5][0]; dc[5]=d[5][1]; dc[6]=d[5][2]; dc[7]=d[5][3];
                    dc[8]=ra1.x-rb1.x; dc[9]=ra1.y-rb1.y; dc[10]=ra1.z-rb1.z; dc[11]=ra1.w-rb1.w;
                    avc[0]=(la1.w+lb1.w)*0.5f;
                    avc[1]=av[2][0]; avc[2]=av[2][1]; avc[3]=av[2][2]; avc[4]=av[2][3];
                    avc[5]=(ra1.x+rb1.x)*0.5f;
                }
                const float y = (float)(h + rr) - 511.5f;
#pragma unroll
                for (int j = 0; j < 4; ++j) {
                    const float px = (avc[j] - avc[j + 2]) * 0.5f;
                    const float py = (av[rr][j] - av[rr + 2][j]) * 0.5f;
                    float ax = lp4 * dc[j + 4];
                    ax = fmaf(lp0, dc[j] + dc[j + 8], ax);
                    ax = fmaf(lp1, dc[j + 1] + dc[j + 7], ax);
                    ax = fmaf(lp2, dc[j + 2] + dc[j + 6], ax);
                    ax = fmaf(lp3, dc[j + 3] + dc[j + 5], ax);
                    float ay = lp4 * d[rr + 4][j];
                    ay = fmaf(lp0, d[rr][j] + d[rr + 8][j], ay);
                    ay = fmaf(lp1, d[rr + 1][j] + d[rr + 7][j], ay);
                    ay = fmaf(lp2, d[rr + 2][j] + d[rr + 6][j], ay);
                    ay = fmaf(lp3, d[rr + 3][j] + d[rr + 5][j], ay);

                    const float x = x0 + (float)j;
                    const float mom = px * y - py * x;
                    s0 = fmaf(px, px, s0);
                    s1 = fmaf(px, py, s1);
                    s2 = fmaf(px, mom, s2);
                    s3 = fmaf(py, py, s3);
                    s4 = fmaf(py, mom, s4);
                    s5 = fmaf(mom, mom, s5);
                    const float tx = ax * px;
                    const float ty = ay * py;
                    s6 += tx;
                    s7 += ty;
                    s8 += tx * y - ty * x;
                }
            }

#pragma unroll
            for (int k = 0; k < 8; ++k) {
                d[k][0]=d[k+2][0]; d[k][1]=d[k+2][1]; d[k][2]=d[k+2][2]; d[k][3]=d[k+2][3];
            }
#pragma unroll
            for (int k = 0; k < 5; ++k) {
                av[k][0]=av[k+2][0]; av[k][1]=av[k+2][1]; av[k][2]=av[k+2][2]; av[k][3]=av[k+2][3];
            }
        }
    }

    // ---- reduction: f64 wave shuffle -> LDS (aliased) -> global atomic ----
    double ds[9];
    ds[0]=s0; ds[1]=s1; ds[2]=s2; ds[3]=s3; ds[4]=s4;
    ds[5]=s5; ds[6]=s6; ds[7]=s7; ds[8]=s8;
#pragma unroll
    for (int k = 0; k < 9; ++k) {
        double x = ds[k];
        for (int off = 32; off > 0; off >>= 1)
            x += __shfl_down(x, off);
        ds[k] = x;
    }
    __syncthreads();                          // full drain; ring no longer needed
    double (*red)[9] = (double(*)[9])smem;
    const int wave = tid >> 6, lane = tid & 63;
    if (lane == 0) {
#pragma unroll
        for (int k = 0; k < 9; ++k) red[wave][k] = ds[k];
    }
    __syncthreads();
    if (tid < 9) {
        double tot = red[0][tid] + red[1][tid];
        atomicAdd(&sums[(size_t)t * 9 + tid], tot);
    }
}

__global__ void gimbaless_solve(const double* __restrict__ sums, float* __restrict__ out)
{
    const int t = threadIdx.x;
    if (t < NFRAMES) {
        const double* s = sums + (size_t)t * 9;
        const double m00=s[0], m01=s[1], m02=s[2], m11=s[3], m12=s[4], m22=s[5];
        const double b0=s[6], b1=s[7], b2=s[8];
        const double c00 = m11*m22 - m12*m12;
        const double c01 = m02*m12 - m01*m22;
        const double c02 = m01*m12 - m02*m11;
        const double c11 = m00*m22 - m02*m02;
        const double c12 = m01*m02 - m00*m12;
        const double c22 = m00*m11 - m01*m01;
        const double det = m00*c00 + m01*c01 + m02*c02;
        const double inv = 1.0 / det;
        out[t]             = (float)((c00*b0 + c01*b1 + c02*b2) * inv);
        out[NFRAMES + t]   = (float)((c01*b0 + c11*b1 + c12*b2) * inv);
        out[2*NFRAMES + t] = (float)((c02*b0 + c12*b1 + c22*b2) * inv);
    }
}

extern "C" void kernel_launch(void* const* d_in, const int* in_sizes, int n_in,
                              void* d_out, int out_size, void* d_ws, size_t ws_size,
                              hipStream_t stream) {
    const float* A  = (const float*)d_in[0];
    const float* B  = (const float*)d_in[1];
    const float* lp = (const float*)d_in[2];
    double* sums = (double*)d_ws;

    (void)hipMemsetAsync(d_ws, 0, NFRAMES * 9 * sizeof(double), stream);

    dim3 grid(2 * ((IMG_H - 2*CROP + RPB - 1) / RPB), NFRAMES);  // (64, 32)
    gimbaless_sums<<<grid, 128, 0, stream>>>(A, B, lp, sums);
    gimbaless_solve<<<1, 64, 0, stream>>>(sums, (float*)d_out);
}

// Round 19
// 78.075 us; speedup vs baseline: 1.9792x; 1.3663x over previous
//
#include <hip/hip_runtime.h>

#define IMG_W 1024
#define IMG_H 1024
#define NFRAMES 32
#define CROP 4
#define RPB 32          // rows per band: 32 bands x 32 frames = 1024 blocks
#define RING 6          // block-shared LDS ring slots (full 4KB rows)
#define ROWB 4096
#define ABYTES (RING*ROWB)   // 24 KiB per tensor; total 48 KiB -> 3 blocks/CU

__device__ __forceinline__ void gl_lds16(const float* g, void* l) {
    __builtin_amdgcn_global_load_lds(
        (const __attribute__((address_space(1))) void*)g,
        (__attribute__((address_space(3))) void*)l,
        16, 0, 0);
}

__global__ __launch_bounds__(256) void gimbaless_sums(
    const float* __restrict__ A, const float* __restrict__ B,
    const float* __restrict__ lp9, double* __restrict__ sums)
{
    __shared__ __align__(16) unsigned char smem[2 * ABYTES];

    const int tid  = threadIdx.x;
    // XCD swizzle (bijective, 32 bands): XCD = blockIdx.x % 8; each XCD gets
    // 4 vertically-contiguous bands -> band-overlap rows become same-L2 hits.
    const int band = (blockIdx.x & 7) * 4 + (blockIdx.x >> 3);
    const int t    = blockIdx.y;
    const float* a = A + (size_t)t * (IMG_W * IMG_H);
    const float* b = B + (size_t)t * (IMG_W * IMG_H);

    const float lp0 = lp9[0], lp1 = lp9[1], lp2 = lp9[2], lp3 = lp9[3], lp4 = lp9[4];

    const int r0   = CROP + band * RPB;
    const int rend = min(r0 + RPB, IMG_H - CROP);   // row count always even

    const int t16 = tid * 16;            // byte offset within a row
    const int wb  = (tid >> 6) * 1024;   // wave-uniform LDS quarter

    auto stage = [&](int r) {            // async DMA full row r of A and B
        const int slot = r % RING;
        gl_lds16(a + (size_t)r * IMG_W + tid * 4, smem + slot * ROWB + wb);
        gl_lds16(b + (size_t)r * IMG_W + tid * 4, smem + ABYTES + slot * ROWB + wb);
    };
    auto rdA = [&](int slot, int off) -> float4 {
        return *(const float4*)(smem + slot * ROWB + off);
    };
    auto rdB = [&](int slot, int off) -> float4 {
        return *(const float4*)(smem + ABYTES + slot * ROWB + off);
    };

    float s0=0.f,s1=0.f,s2=0.f,s3=0.f,s4=0.f,s5=0.f,s6=0.f,s7=0.f,s8=0.f;
    float d[10][4];   // dif rows h-4 .. h+5
    float av[7][4];   // avg rows h-1 .. h+5
    const bool active = ((unsigned)(tid - 1) < 254u);
    const int w0 = 4 * tid;
    const float x0 = (float)w0 - 511.5f;

    // ---- prologue: fill window rows r0-4..r0+3 (d[0..7], av[0..4]) ----
    for (int r = r0 - 4; r <= r0 + 1; ++r) stage(r);          // 6 rows fill ring
    asm volatile("s_waitcnt vmcnt(0)" ::: "memory");          // own chunks arrived
    if (active) {
#pragma unroll
        for (int k = 0; k < 6; ++k) {                         // rows r0-4..r0+1 (own chunk)
            const int slot = (r0 - 4 + k) % RING;
            float4 va = rdA(slot, t16);
            float4 vb = rdB(slot, t16);
            d[k][0]=va.x-vb.x; d[k][1]=va.y-vb.y; d[k][2]=va.z-vb.z; d[k][3]=va.w-vb.w;
            if (k >= 3) {
                av[k-3][0]=(va.x+vb.x)*0.5f; av[k-3][1]=(va.y+vb.y)*0.5f;
                av[k-3][2]=(va.z+vb.z)*0.5f; av[k-3][3]=(va.w+vb.w)*0.5f;
            }
        }
    }
    asm volatile("s_waitcnt lgkmcnt(0)" ::: "memory");        // reads landed before overwrite
    stage(r0 + 2); stage(r0 + 3); stage(r0 + 4); stage(r0 + 5);
    asm volatile("s_waitcnt vmcnt(4)" ::: "memory");          // r0+2, r0+3 arrived
    if (active) {
#pragma unroll
        for (int k = 6; k < 8; ++k) {                         // rows r0+2, r0+3
            const int slot = (r0 - 4 + k) % RING;
            float4 va = rdA(slot, t16);
            float4 vb = rdB(slot, t16);
            d[k][0]=va.x-vb.x; d[k][1]=va.y-vb.y; d[k][2]=va.z-vb.z; d[k][3]=va.w-vb.w;
            av[k-3][0]=(va.x+vb.x)*0.5f; av[k-3][1]=(va.y+vb.y)*0.5f;
            av[k-3][2]=(va.z+vb.z)*0.5f; av[k-3][3]=(va.w+vb.w)*0.5f;
        }
    }
    // in flight entering loop: stage(r0+4), stage(r0+5)  (4 DMA ops)

    // ---- main loop: 2 rows per iteration ----
#pragma unroll 1
    for (int h = r0; h < rend; h += 2) {
        asm volatile("s_waitcnt vmcnt(0)" ::: "memory");  // rows h+4,h+5 arrived
        __builtin_amdgcn_s_barrier();                     // all waves' chunks visible

        const int m0 = h % RING;                          // slot of row h (reused by h+6)
        const int m1 = (h + 1) % RING;
        const int m4 = (h + 4) % RING;
        const int m5 = (h + 5) % RING;

        // ---- all LDS reads up front ----
        float4 na0, nb0, na1, nb1, la0, lb0, ra0, rb0, la1, lb1, ra1, rb1;
        if (active) {
            na0 = rdA(m4, t16);      nb0 = rdB(m4, t16);
            na1 = rdA(m5, t16);      nb1 = rdB(m5, t16);
            la0 = rdA(m0, t16 - 16); lb0 = rdB(m0, t16 - 16);
            ra0 = rdA(m0, t16 + 16); rb0 = rdB(m0, t16 + 16);
            la1 = rdA(m1, t16 - 16); lb1 = rdB(m1, t16 - 16);
            ra1 = rdA(m1, t16 + 16); rb1 = rdB(m1, t16 + 16);
        }
        asm volatile("s_waitcnt lgkmcnt(0)" ::: "memory"); // reads in registers
        __builtin_amdgcn_s_barrier();                      // safe to overwrite m0,m1

        if (h + 2 < rend) { stage(h + 6); stage(h + 7); }  // DMA runs under compute

        if (active) {
            d[8][0]=na0.x-nb0.x; d[8][1]=na0.y-nb0.y; d[8][2]=na0.z-nb0.z; d[8][3]=na0.w-nb0.w;
            av[5][0]=(na0.x+nb0.x)*0.5f; av[5][1]=(na0.y+nb0.y)*0.5f;
            av[5][2]=(na0.z+nb0.z)*0.5f; av[5][3]=(na0.w+nb0.w)*0.5f;
            d[9][0]=na1.x-nb1.x; d[9][1]=na1.y-nb1.y; d[9][2]=na1.z-nb1.z; d[9][3]=na1.w-nb1.w;
            av[6][0]=(na1.x+nb1.x)*0.5f; av[6][1]=(na1.y+nb1.y)*0.5f;
            av[6][2]=(na1.z+nb1.z)*0.5f; av[6][3]=(na1.w+nb1.w)*0.5f;

#pragma unroll
            for (int rr = 0; rr < 2; ++rr) {              // rows h, h+1
                float dc[12], avc[6];
                if (rr == 0) {
                    dc[0]=la0.x-lb0.x; dc[1]=la0.y-lb0.y; dc[2]=la0.z-lb0.z; dc[3]=la0.w-lb0.w;
                    dc[4]=d[4][0]; dc[5]=d[4][1]; dc[6]=d[4][2]; dc[7]=d[4][3];
                    dc[8]=ra0.x-rb0.x; dc[9]=ra0.y-rb0.y; dc[10]=ra0.z-rb0.z; dc[11]=ra0.w-rb0.w;
                    avc[0]=(la0.w+lb0.w)*0.5f;
                    avc[1]=av[1][0]; avc[2]=av[1][1]; avc[3]=av[1][2]; avc[4]=av[1][3];
                    avc[5]=(ra0.x+rb0.x)*0.5f;
                } else {
                    dc[0]=la1.x-lb1.x; dc[1]=la1.y-lb1.y; dc[2]=la1.z-lb1.z; dc[3]=la1.w-lb1.w;
                    dc[4]=d[5][0]; dc[5]=d[5][1]; dc[6]=d[5][2]; dc[7]=d[5][3];
                    dc[8]=ra1.x-rb1.x; dc[9]=ra1.y-rb1.y; dc[10]=ra1.z-rb1.z; dc[11]=ra1.w-rb1.w;
                    avc[0]=(la1.w+lb1.w)*0.5f;
                    avc[1]=av[2][0]; avc[2]=av[2][1]; avc[3]=av[2][2]; avc[4]=av[2][3];
                    avc[5]=(ra1.x+rb1.x)*0.5f;
                }
                const float y = (float)(h + rr) - 511.5f;
#pragma unroll
                for (int j = 0; j < 4; ++j) {
                    const float px = (avc[j] - avc[j + 2]) * 0.5f;
                    const float py = (av[rr][j] - av[rr + 2][j]) * 0.5f;
                    float ax = lp4 * dc[j + 4];
                    ax = fmaf(lp0, dc[j] + dc[j + 8], ax);
                    ax = fmaf(lp1, dc[j + 1] + dc[j + 7], ax);
                    ax = fmaf(lp2, dc[j + 2] + dc[j + 6], ax);
                    ax = fmaf(lp3, dc[j + 3] + dc[j + 5], ax);
                    float ay = lp4 * d[rr + 4][j];
                    ay = fmaf(lp0, d[rr][j] + d[rr + 8][j], ay);
                    ay = fmaf(lp1, d[rr + 1][j] + d[rr + 7][j], ay);
                    ay = fmaf(lp2, d[rr + 2][j] + d[rr + 6][j], ay);
                    ay = fmaf(lp3, d[rr + 3][j] + d[rr + 5][j], ay);

                    const float x = x0 + (float)j;
                    const float mom = px * y - py * x;
                    s0 = fmaf(px, px, s0);
                    s1 = fmaf(px, py, s1);
                    s2 = fmaf(px, mom, s2);
                    s3 = fmaf(py, py, s3);
                    s4 = fmaf(py, mom, s4);
                    s5 = fmaf(mom, mom, s5);
                    const float tx = ax * px;
                    const float ty = ay * py;
                    s6 += tx;
                    s7 += ty;
                    s8 += tx * y - ty * x;
                }
            }

#pragma unroll
            for (int k = 0; k < 8; ++k) {
                d[k][0]=d[k+2][0]; d[k][1]=d[k+2][1]; d[k][2]=d[k+2][2]; d[k][3]=d[k+2][3];
            }
#pragma unroll
            for (int k = 0; k < 5; ++k) {
                av[k][0]=av[k+2][0]; av[k][1]=av[k+2][1]; av[k][2]=av[k+2][2]; av[k][3]=av[k+2][3];
            }
        }
    }

    // ---- reduction: f64 wave shuffle -> LDS (aliased) -> global atomic ----
    double ds[9];
    ds[0]=s0; ds[1]=s1; ds[2]=s2; ds[3]=s3; ds[4]=s4;
    ds[5]=s5; ds[6]=s6; ds[7]=s7; ds[8]=s8;
#pragma unroll
    for (int k = 0; k < 9; ++k) {
        double x = ds[k];
        for (int off = 32; off > 0; off >>= 1)
            x += __shfl_down(x, off);
        ds[k] = x;
    }
    __syncthreads();                          // everyone past ring use (full drain)
    double (*red)[9] = (double(*)[9])smem;    // alias ring buffer
    const int wave = tid >> 6, lane = tid & 63;
    if (lane == 0) {
#pragma unroll
        for (int k = 0; k < 9; ++k) red[wave][k] = ds[k];
    }
    __syncthreads();
    if (tid < 9) {
        double tot = red[0][tid] + red[1][tid] + red[2][tid] + red[3][tid];
        atomicAdd(&sums[(size_t)t * 9 + tid], tot);
    }
}

__global__ void gimbaless_solve(const double* __restrict__ sums, float* __restrict__ out)
{
    const int t = threadIdx.x;
    if (t < NFRAMES) {
        const double* s = sums + (size_t)t * 9;
        const double m00=s[0], m01=s[1], m02=s[2], m11=s[3], m12=s[4], m22=s[5];
        const double b0=s[6], b1=s[7], b2=s[8];
        const double c00 = m11*m22 - m12*m12;
        const double c01 = m02*m12 - m01*m22;
        const double c02 = m01*m12 - m02*m11;
        const double c11 = m00*m22 - m02*m02;
        const double c12 = m01*m02 - m00*m12;
        const double c22 = m00*m11 - m01*m01;
        const double det = m00*c00 + m01*c01 + m02*c02;
        const double inv = 1.0 / det;
        out[t]             = (float)((c00*b0 + c01*b1 + c02*b2) * inv);
        out[NFRAMES + t]   = (float)((c01*b0 + c11*b1 + c12*b2) * inv);
        out[2*NFRAMES + t] = (float)((c02*b0 + c12*b1 + c22*b2) * inv);
    }
}

extern "C" void kernel_launch(void* const* d_in, const int* in_sizes, int n_in,
                              void* d_out, int out_size, void* d_ws, size_t ws_size,
                              hipStream_t stream) {
    const float* A  = (const float*)d_in[0];
    const float* B  = (const float*)d_in[1];
    const float* lp = (const float*)d_in[2];
    double* sums = (double*)d_ws;

    (void)hipMemsetAsync(d_ws, 0, NFRAMES * 9 * sizeof(double), stream);

    dim3 grid((IMG_H - 2*CROP + RPB - 1) / RPB, NFRAMES);  // (32, 32)
    gimbaless_sums<<<grid, 256, 0, stream>>>(A, B, lp, sums);
    gimbaless_solve<<<1, 64, 0, stream>>>(sums, (float*)d_out);
}